// Round 16
// baseline (60.072 us; speedup 1.0000x reference)
//
#include <hip/hip_runtime.h>
#include <hip/hip_bf16.h>
#include <float.h>

// Problem constants (from reference setup_inputs)
#define B_  4
#define C_  256
#define H_  50
#define W_  50
#define R_  300
#define PH_ 7
#define PW_ 7
#define S_  (H_ * W_)        // 2500
#define Q_  (PH_ * PW_)      // 49
#define SC_ (S_ * C_)        // 640000 floats per batch image
#define ARRN (B_ * SC_)      // 2,560,000 floats per table
#define CQ_  64              // channels per pool block
#define NCQ  (C_ / CQ_)      // 4
#define NWG_POOL (R_ * NCQ)  // 1200 (divisible by 8)
#define REP_ 3               // DIAGNOSTIC: K2 repeats its work 3x (identical
                             // output each pass) so the dispatch rises above
                             // the ~40us harness fills in the rocprof top-5
                             // and dur_us = K1 + 3*K2 decomposes the split.

// ---------------------------------------------------------------------------
// Kernel K1 (R10-proven): transpose fm [B,C,S] -> fmT [B,S,C], build span
// tables P2 (w..w+1 row-clamped max), P4 (w..w+3).
// ---------------------------------------------------------------------------
__global__ __launch_bounds__(256) void transpose_tables(
    const float* __restrict__ fm,   // [B, C, S]
    float* __restrict__ fmT,        // [B, S, C]
    float* __restrict__ P2,         // [B, S, C]
    float* __restrict__ P4)         // [B, S, C]
{
    __shared__ float tile[64][69];

    const int b  = blockIdx.z;
    const int c0 = blockIdx.y * 64;           // 256/64 = 4
    const int s0 = blockIdx.x * 64;           // 40 tiles cover 2500

    const int tx = threadIdx.x;               // 0..63 (lane)
    const int ty = threadIdx.y;               // 0..3  (wave)

    if (s0 + tx < S_) {
        #pragma unroll
        for (int j = 0; j < 16; ++j) {
            const int c = c0 + ty + j * 4;
            tile[ty + j * 4][tx] = fm[((size_t)b * C_ + c) * S_ + (s0 + tx)];
        }
    }
    if (tx < 4 && s0 + 64 + tx < S_) {
        #pragma unroll
        for (int j = 0; j < 16; ++j) {
            const int c = c0 + ty + j * 4;
            tile[ty + j * 4][64 + tx] = fm[((size_t)b * C_ + c) * S_ + (s0 + 64 + tx)];
        }
    }
    __syncthreads();

    #pragma unroll
    for (int j = 0; j < 16; ++j) {
        const int s = s0 + ty + j * 4;
        if (s < S_) {
            const int ls  = ty + j * 4;
            const int w   = s % W_;                    // wave-uniform
            const int rem = W_ - 1 - w;                // valid same-row nbrs
            const float v0 = tile[tx][ls];
            float p2 = (rem >= 1) ? fmaxf(v0, tile[tx][ls + 1]) : v0;
            float p4 = p2;
            if (rem >= 2) p4 = fmaxf(p4, tile[tx][ls + 2]);
            if (rem >= 3) p4 = fmaxf(p4, tile[tx][ls + 3]);

            const size_t o = ((size_t)b * S_ + s) * C_ + (c0 + tx);
            fmT[o] = v0;
            P2[o]  = p2;
            P4[o]  = p4;
        }
    }
}

// ---------------------------------------------------------------------------
// Block-uniform ROI decode (SPATIAL_SCALE == 1.0); matches reference exactly.
// ---------------------------------------------------------------------------
__device__ __forceinline__ void roi_decode(const float* __restrict__ rois, int r,
                                           int& b, int& x0, int& y0,
                                           int& roi_w, int& roi_h)
{
    const float* rp = rois + r * 5;
    b = (int)rp[4];                          // trunc, matches astype(int32)
    // jnp.round == round-half-to-even == rintf
    x0      = (int)rintf(rp[0]);
    y0      = (int)rintf(rp[1]);
    int x1  = (int)rintf(rp[2]);
    int y1  = (int)rintf(rp[3]);
    x0 = min(max(x0, 0), W_ - 1);
    x1 = min(max(x1, 0), W_ - 1);
    y0 = min(max(y0, 0), H_ - 1);
    y1 = min(max(y1, 0), H_ - 1);
    x1 = max(x1, x0 + 1);
    y1 = max(y1, y0 + 1);
    roi_w = x1 - x0;                         // >= 1  (bin widths  <= 8)
    roi_h = y1 - y0;                         // >= 1  (bin heights <= 8)
}

// ---------------------------------------------------------------------------
// K2 pool phase (R10-proven math): branchless per-bin pooling, WH =
// block-uniform max bin height. Span tables sp=4/2/1 -> anchors ws, we-sp
// union exactly to [ws,we) for ww 1..8. Rows: min(hs+kh,he-1) clamp.
// ---------------------------------------------------------------------------
template<int WH>
__device__ __forceinline__ void pool_bins(
    const float* __restrict__ fmT, const float* __restrict__ P2,
    const float* __restrict__ P4, float* __restrict__ buf,
    int wv, int lane, int imgC,
    int x0, int y0, int roi_w, int roi_h)
{
    const int start = wv * 12 + (wv ? 1 : 0);
    const int qlast = wv * 12 + 12;

    #pragma unroll 2
    for (int k = 0; k < 13; ++k) {
        int q = start + k;
        q = (q > qlast) ? qlast : q;
        const int ph = q / PW_;
        const int pw = q - ph * PW_;
        const int ws = x0 + (pw * roi_w) / PW_;
        const int we = x0 + ((pw + 1) * roi_w + PW_ - 1) / PW_;
        const int hs = y0 + (ph * roi_h) / PH_;
        const int he = y0 + ((ph + 1) * roi_h + PH_ - 1) / PH_;
        const int ww = we - ws;              // 1..8

        const int sp = (ww >= 4) ? 4 : ((ww >= 2) ? 2 : 1);
        const float* tb = (ww >= 4) ? P4 : ((ww >= 2) ? P2 : fmT);
        const int colB = we - sp;

        float va[WH], vb[WH];
        #pragma unroll
        for (int kh = 0; kh < WH; ++kh) {
            int row = hs + kh;
            row = (row > he - 1) ? (he - 1) : row;        // clamp (in-window)
            const int ro = imgC + row * (W_ * C_);
            va[kh] = tb[ro + ws * C_];
            vb[kh] = tb[ro + colB * C_];
        }
        float m = -FLT_MAX;
        #pragma unroll
        for (int kh = 0; kh < WH; ++kh)
            m = fmaxf(m, fmaxf(va[kh], vb[kh]));

        buf[q * 65 + lane] = m;
    }
}

__global__ __launch_bounds__(256) void roi_pool_tables(
    const float* __restrict__ fmT,   // [B, S, C]
    const float* __restrict__ P2,    // [B, S, C]
    const float* __restrict__ P4,    // [B, S, C]
    const float* __restrict__ rois,  // [R, 5]
    float* __restrict__ out)         // [R, C, Q]
{
    __shared__ float buf[Q_ * 65];           // 12740 B

    // XCD-chunked swizzle (1200 % 8 == 0 -> bijective)
    const int bid = blockIdx.x;
    const int swz = (bid & 7) * (NWG_POOL / 8) + (bid >> 3);
    const int r   = swz >> 2;
    const int c0  = (swz & (NCQ - 1)) * CQ_;

    const int t    = threadIdx.x;
    const int wv   = t >> 6;
    const int lane = t & 63;

    int b, x0, y0, roi_w, roi_h;
    roi_decode(rois, r, b, x0, y0, roi_w, roi_h);

    // exact block-uniform max bin height
    int whmax = 1;
    #pragma unroll
    for (int i = 0; i < PH_; ++i) {
        const int hs = (i * roi_h) / PH_;
        const int he = ((i + 1) * roi_h + PH_ - 1) / PH_;
        whmax = max(whmax, he - hs);
    }

    const int imgC = b * SC_ + c0 + lane;    // < 2.56M, fits int32

    // DIAGNOSTIC loop: each pass recomputes and rewrites the IDENTICAL
    // output (deterministic; absmax unchanged). The memory clobber stops
    // LLVM from hoisting the (restrict, loop-invariant) table loads out of
    // the loop — each pass re-issues every global read, so counters and
    // duration scale ~3x and dur_us = K1 + 3*K2.
    for (int rep = 0; rep < REP_; ++rep) {
        asm volatile("" ::: "memory");

        switch (whmax) {                     // block-uniform dispatch
            case 1: pool_bins<1>(fmT, P2, P4, buf, wv, lane, imgC, x0, y0, roi_w, roi_h); break;
            case 2: pool_bins<2>(fmT, P2, P4, buf, wv, lane, imgC, x0, y0, roi_w, roi_h); break;
            case 3: pool_bins<3>(fmT, P2, P4, buf, wv, lane, imgC, x0, y0, roi_w, roi_h); break;
            case 4: pool_bins<4>(fmT, P2, P4, buf, wv, lane, imgC, x0, y0, roi_w, roi_h); break;
            case 5: pool_bins<5>(fmT, P2, P4, buf, wv, lane, imgC, x0, y0, roi_w, roi_h); break;
            case 6: pool_bins<6>(fmT, P2, P4, buf, wv, lane, imgC, x0, y0, roi_w, roi_h); break;
            case 7: pool_bins<7>(fmT, P2, P4, buf, wv, lane, imgC, x0, y0, roi_w, roi_h); break;
            default: pool_bins<8>(fmT, P2, P4, buf, wv, lane, imgC, x0, y0, roi_w, roi_h); break;
        }
        __syncthreads();

        // block-exclusive coalesced write: out[r, c0..c0+64, 0..49)
        float* outp = out + ((size_t)r * C_ + c0) * Q_;
        #pragma unroll
        for (int k = 0; k < 13; ++k) {
            const int e = k * 256 + t;
            if (e < CQ_ * Q_) {
                const int cl = e / Q_;
                const int q  = e - cl * Q_;
                outp[e] = buf[q * 65 + cl];
            }
        }
        __syncthreads();                     // buf reuse across passes
    }
}

// ---------------------------------------------------------------------------
// Fallback (ws too small): round-1 thread-per-output kernel (proven, 42.7 us).
// ---------------------------------------------------------------------------
__global__ __launch_bounds__(256) void roi_pool_naive(
    const float* __restrict__ fm,    // [B, C, H, W]
    const float* __restrict__ rois,
    float* __restrict__ out)
{
    const int total = R_ * C_ * Q_;
    int t = blockIdx.x * blockDim.x + threadIdx.x;
    if (t >= total) return;
    int q   = t % Q_;
    int tmp = t / Q_;
    int pw  = q % PW_;
    int ph  = q / PW_;
    int c   = tmp % C_;
    int r   = tmp / C_;

    int b, x0, y0, roi_w, roi_h;
    roi_decode(rois, r, b, x0, y0, roi_w, roi_h);

    const int ws = x0 + (pw * roi_w) / PW_;
    const int we = x0 + ((pw + 1) * roi_w + PW_ - 1) / PW_;
    const int hs = y0 + (ph * roi_h) / PH_;
    const int he = y0 + ((ph + 1) * roi_h + PH_ - 1) / PH_;

    const float* p = fm + ((size_t)(b * C_ + c)) * S_;
    float m = -FLT_MAX;
    for (int h = hs; h < he; ++h)
        for (int w = ws; w < we; ++w)
            m = fmaxf(m, p[h * W_ + w]);
    out[t] = m;
}

extern "C" void kernel_launch(void* const* d_in, const int* in_sizes, int n_in,
                              void* d_out, int out_size, void* d_ws, size_t ws_size,
                              hipStream_t stream)
{
    const float* fm   = (const float*)d_in[0];  // [4,256,50,50]
    const float* rois = (const float*)d_in[1];  // [300,5]
    float* out        = (float*)d_out;          // [300,256,7,7]

    const size_t NEED = 3 * (size_t)ARRN * sizeof(float);   // 30.72 MB

    if (ws_size >= NEED) {
        float* fmT = (float*)d_ws;
        float* P2  = fmT + ARRN;
        float* P4  = P2 + ARRN;
        {
            dim3 grid(40, C_ / 64, B_);          // 40 s-tiles x 4 c-tiles x 4 batch
            dim3 block(64, 4, 1);
            transpose_tables<<<grid, block, 0, stream>>>(fm, fmT, P2, P4);
        }
        roi_pool_tables<<<NWG_POOL, 256, 0, stream>>>(fmT, P2, P4, rois, out);
    } else {
        const int total = R_ * C_ * Q_;
        roi_pool_naive<<<(total + 255) / 256, 256, 0, stream>>>(fm, rois, out);
    }
}

// Round 17
// 44.163 us; speedup vs baseline: 1.3602x; 1.3602x over previous
//
#include <hip/hip_runtime.h>
#include <hip/hip_bf16.h>
#include <float.h>

// Problem constants (from reference setup_inputs)
#define B_  4
#define C_  256
#define H_  50
#define W_  50
#define R_  300
#define PH_ 7
#define PW_ 7
#define S_  (H_ * W_)        // 2500
#define Q_  (PH_ * PW_)      // 49
#define SC_ (S_ * C_)        // 640000 floats per batch image
#define ARRN (B_ * SC_)      // 2,560,000 floats per table
#define CQ_  64              // channels per pool block
#define NCQ  (C_ / CQ_)      // 4
#define NWG_POOL (R_ * NCQ)  // 1200 (divisible by 8)

// ---------------------------------------------------------------------------
// Kernel K1 (R10-proven): transpose fm [B,C,S] -> fmT [B,S,C], build span
// tables P2 (w..w+1 row-clamped max), P4 (w..w+3). The three tables are
// allocated CONTIGUOUSLY (P2 = fmT + ARRN, P4 = P2 + ARRN) so K2 can fold
// table selection into a precomputed element offset.
// ---------------------------------------------------------------------------
__global__ __launch_bounds__(256) void transpose_tables(
    const float* __restrict__ fm,   // [B, C, S]
    float* __restrict__ fmT,        // [B, S, C]
    float* __restrict__ P2,         // [B, S, C]
    float* __restrict__ P4)         // [B, S, C]
{
    __shared__ float tile[64][69];

    const int b  = blockIdx.z;
    const int c0 = blockIdx.y * 64;           // 256/64 = 4
    const int s0 = blockIdx.x * 64;           // 40 tiles cover 2500

    const int tx = threadIdx.x;               // 0..63 (lane)
    const int ty = threadIdx.y;               // 0..3  (wave)

    if (s0 + tx < S_) {
        #pragma unroll
        for (int j = 0; j < 16; ++j) {
            const int c = c0 + ty + j * 4;
            tile[ty + j * 4][tx] = fm[((size_t)b * C_ + c) * S_ + (s0 + tx)];
        }
    }
    if (tx < 4 && s0 + 64 + tx < S_) {
        #pragma unroll
        for (int j = 0; j < 16; ++j) {
            const int c = c0 + ty + j * 4;
            tile[ty + j * 4][64 + tx] = fm[((size_t)b * C_ + c) * S_ + (s0 + 64 + tx)];
        }
    }
    __syncthreads();

    #pragma unroll
    for (int j = 0; j < 16; ++j) {
        const int s = s0 + ty + j * 4;
        if (s < S_) {
            const int ls  = ty + j * 4;
            const int w   = s % W_;                    // wave-uniform
            const int rem = W_ - 1 - w;                // valid same-row nbrs
            const float v0 = tile[tx][ls];
            float p2 = (rem >= 1) ? fmaxf(v0, tile[tx][ls + 1]) : v0;
            float p4 = p2;
            if (rem >= 2) p4 = fmaxf(p4, tile[tx][ls + 2]);
            if (rem >= 3) p4 = fmaxf(p4, tile[tx][ls + 3]);

            const size_t o = ((size_t)b * S_ + s) * C_ + (c0 + tx);
            fmT[o] = v0;
            P2[o]  = p2;
            P4[o]  = p4;
        }
    }
}

// ---------------------------------------------------------------------------
// Block-uniform ROI decode (SPATIAL_SCALE == 1.0); matches reference exactly.
// ---------------------------------------------------------------------------
__device__ __forceinline__ void roi_decode(const float* __restrict__ rois, int r,
                                           int& b, int& x0, int& y0,
                                           int& roi_w, int& roi_h)
{
    const float* rp = rois + r * 5;
    b = (int)rp[4];                          // trunc, matches astype(int32)
    // jnp.round == round-half-to-even == rintf
    x0      = (int)rintf(rp[0]);
    y0      = (int)rintf(rp[1]);
    int x1  = (int)rintf(rp[2]);
    int y1  = (int)rintf(rp[3]);
    x0 = min(max(x0, 0), W_ - 1);
    x1 = min(max(x1, 0), W_ - 1);
    y0 = min(max(y0, 0), H_ - 1);
    y1 = min(max(y1, 0), H_ - 1);
    x1 = max(x1, x0 + 1);
    y1 = max(y1, y0 + 1);
    roi_w = x1 - x0;                         // >= 1  (bin widths  <= 8)
    roi_h = y1 - y0;                         // >= 1  (bin heights <= 8)
}

// ---------------------------------------------------------------------------
// Kernel K2 (VALU-debloated per R16 counters: VALUBusy 52% was redundant
// wave-uniform edge/address math + whmax padding):
//   Phase 1 (once per block, parallel): 49 bins x wh rows -> FINAL element
//     offsets oA/oB (table select folded: + sel*ARRN; anchors ws / we-sp
//     whose spans union EXACTLY to [ws,we), proven R7-R16) + per-bin wh,
//     all in LDS.
//   Phase 2: per-wave bin loop; per row-pair: ds_read_b64 (uniform
//     broadcast, LDS pipe) + 1 add + 2 loads + 2 fmax. No clamp (kh < wh),
//     no div-by-7, no 64-bit math, no template padding -> VALU freed and
//     tall-ROI tail shrunk (loads = exact 2*sum(wh), not 2*13*whmax).
// ---------------------------------------------------------------------------
__global__ __launch_bounds__(256) void roi_pool_tables(
    const float* __restrict__ fmT,   // [B, S, C] (+ARRN: P2, +2*ARRN: P4)
    const float* __restrict__ rois,  // [R, 5]
    float* __restrict__ out)         // [R, C, Q]
{
    __shared__ float buf[Q_ * 65];           // 12740 B staging
    __shared__ int2  oAB[Q_ * 8];            // 3136 B: per (bin, row) offsets
    __shared__ int   whA[Q_];                // per-bin row count

    // XCD-chunked swizzle (1200 % 8 == 0 -> bijective)
    const int bid = blockIdx.x;
    const int swz = (bid & 7) * (NWG_POOL / 8) + (bid >> 3);
    const int r   = swz >> 2;
    const int c0  = (swz & (NCQ - 1)) * CQ_;

    const int t    = threadIdx.x;
    const int wv   = t >> 6;
    const int lane = t & 63;

    int b, x0, y0, roi_w, roi_h;
    roi_decode(rois, r, b, x0, y0, roi_w, roi_h);

    // ---- Phase 1: parallel offset precompute (392 items over 256 thr) ----
    for (int idx = t; idx < Q_ * 8; idx += 256) {
        const int q  = idx >> 3;
        const int kh = idx & 7;
        const int ph = q / PW_;
        const int pw = q - ph * PW_;
        const int ws = x0 + (pw * roi_w) / PW_;
        const int we = x0 + ((pw + 1) * roi_w + PW_ - 1) / PW_;
        const int hs = y0 + (ph * roi_h) / PH_;
        const int he = y0 + ((ph + 1) * roi_h + PH_ - 1) / PH_;
        const int ww = we - ws;              // 1..8
        const int wh = he - hs;              // 1..8
        if (kh == 0) whA[q] = wh;
        if (kh < wh) {
            const int sp  = (ww >= 4) ? 4 : ((ww >= 2) ? 2 : 1);
            const int sel = (ww >= 4) ? 2 : ((ww >= 2) ? 1 : 0);
            const int row = hs + kh;         // kh < wh -> always in-window
            const int rb  = sel * ARRN + (row * W_) * C_;
            oAB[idx] = make_int2(rb + ws * C_, rb + (we - sp) * C_);
        }
    }
    __syncthreads();

    const int imgC = b * SC_ + c0 + lane;    // per-lane element base (int32)

    // ---- Phase 2: pool. Wave q-ranges: 0-12, 13-24, 25-36, 37-48 ----
    const int qstart = wv * 12 + (wv ? 1 : 0);
    const int qend   = wv * 12 + 12;
    for (int q = qstart; q <= qend; ++q) {
        const int wh = whA[q];               // uniform broadcast
        float m = -FLT_MAX;
        #pragma unroll 2
        for (int kh = 0; kh < wh; ++kh) {    // wave-uniform trip count
            const int2 o = oAB[q * 8 + kh];  // ds_read_b64, broadcast
            m = fmaxf(m, fmaxf(fmT[imgC + o.x], fmT[imgC + o.y]));
        }
        buf[q * 65 + lane] = m;
    }
    __syncthreads();

    // block-exclusive coalesced write: out[r, c0..c0+64, 0..49)
    float* outp = out + ((size_t)r * C_ + c0) * Q_;
    #pragma unroll
    for (int k = 0; k < 13; ++k) {
        const int e = k * 256 + t;
        if (e < CQ_ * Q_) {
            const int cl = e / Q_;
            const int q  = e - cl * Q_;
            outp[e] = buf[q * 65 + cl];
        }
    }
}

// ---------------------------------------------------------------------------
// Fallback (ws too small): round-1 thread-per-output kernel (proven, 42.7 us).
// ---------------------------------------------------------------------------
__global__ __launch_bounds__(256) void roi_pool_naive(
    const float* __restrict__ fm,    // [B, C, H, W]
    const float* __restrict__ rois,
    float* __restrict__ out)
{
    const int total = R_ * C_ * Q_;
    int t = blockIdx.x * blockDim.x + threadIdx.x;
    if (t >= total) return;
    int q   = t % Q_;
    int tmp = t / Q_;
    int pw  = q % PW_;
    int ph  = q / PW_;
    int c   = tmp % C_;
    int r   = tmp / C_;

    int b, x0, y0, roi_w, roi_h;
    roi_decode(rois, r, b, x0, y0, roi_w, roi_h);

    const int ws = x0 + (pw * roi_w) / PW_;
    const int we = x0 + ((pw + 1) * roi_w + PW_ - 1) / PW_;
    const int hs = y0 + (ph * roi_h) / PH_;
    const int he = y0 + ((ph + 1) * roi_h + PH_ - 1) / PH_;

    const float* p = fm + ((size_t)(b * C_ + c)) * S_;
    float m = -FLT_MAX;
    for (int h = hs; h < he; ++h)
        for (int w = ws; w < we; ++w)
            m = fmaxf(m, p[h * W_ + w]);
    out[t] = m;
}

extern "C" void kernel_launch(void* const* d_in, const int* in_sizes, int n_in,
                              void* d_out, int out_size, void* d_ws, size_t ws_size,
                              hipStream_t stream)
{
    const float* fm   = (const float*)d_in[0];  // [4,256,50,50]
    const float* rois = (const float*)d_in[1];  // [300,5]
    float* out        = (float*)d_out;          // [300,256,7,7]

    const size_t NEED = 3 * (size_t)ARRN * sizeof(float);   // 30.72 MB

    if (ws_size >= NEED) {
        float* fmT = (float*)d_ws;
        float* P2  = fmT + ARRN;                // contiguous: offset ARRN
        float* P4  = P2 + ARRN;                 // contiguous: offset 2*ARRN
        {
            dim3 grid(40, C_ / 64, B_);         // 40 s-tiles x 4 c-tiles x 4 batch
            dim3 block(64, 4, 1);
            transpose_tables<<<grid, block, 0, stream>>>(fm, fmT, P2, P4);
        }
        roi_pool_tables<<<NWG_POOL, 256, 0, stream>>>(fmT, rois, out);
    } else {
        const int total = R_ * C_ * Q_;
        roi_pool_naive<<<(total + 255) / 256, 256, 0, stream>>>(fm, rois, out);
    }
}

// Round 18
// 38.339 us; speedup vs baseline: 1.5669x; 1.1519x over previous
//
#include <hip/hip_runtime.h>
#include <hip/hip_bf16.h>
#include <float.h>

// Problem constants (from reference setup_inputs)
#define B_  4
#define C_  256
#define H_  50
#define W_  50
#define R_  300
#define PH_ 7
#define PW_ 7
#define S_  (H_ * W_)        // 2500
#define Q_  (PH_ * PW_)      // 49
#define SC_ (S_ * C_)        // 640000 floats per batch image
#define ARRN (B_ * SC_)      // 2,560,000 floats per table
#define CE_  32              // channels per pool block (eighth)
#define NE_  8               // eighths
#define NWG_POOL (R_ * NE_)  // 2400 blocks -> 8 blocks/CU (full occupancy)

// ---------------------------------------------------------------------------
// Kernel K1 (R10-proven, byte-identical): transpose fm [B,C,S] -> fmT [B,S,C],
// build span tables P2 (w..w+1 row-clamped max), P4 (w..w+3).
// ---------------------------------------------------------------------------
__global__ __launch_bounds__(256) void transpose_tables(
    const float* __restrict__ fm,   // [B, C, S]
    float* __restrict__ fmT,        // [B, S, C]
    float* __restrict__ P2,         // [B, S, C]
    float* __restrict__ P4)         // [B, S, C]
{
    __shared__ float tile[64][69];

    const int b  = blockIdx.z;
    const int c0 = blockIdx.y * 64;           // 256/64 = 4
    const int s0 = blockIdx.x * 64;           // 40 tiles cover 2500

    const int tx = threadIdx.x;               // 0..63 (lane)
    const int ty = threadIdx.y;               // 0..3  (wave)

    if (s0 + tx < S_) {
        #pragma unroll
        for (int j = 0; j < 16; ++j) {
            const int c = c0 + ty + j * 4;
            tile[ty + j * 4][tx] = fm[((size_t)b * C_ + c) * S_ + (s0 + tx)];
        }
    }
    if (tx < 4 && s0 + 64 + tx < S_) {
        #pragma unroll
        for (int j = 0; j < 16; ++j) {
            const int c = c0 + ty + j * 4;
            tile[ty + j * 4][64 + tx] = fm[((size_t)b * C_ + c) * S_ + (s0 + 64 + tx)];
        }
    }
    __syncthreads();

    #pragma unroll
    for (int j = 0; j < 16; ++j) {
        const int s = s0 + ty + j * 4;
        if (s < S_) {
            const int ls  = ty + j * 4;
            const int w   = s % W_;                    // wave-uniform
            const int rem = W_ - 1 - w;                // valid same-row nbrs
            const float v0 = tile[tx][ls];
            float p2 = (rem >= 1) ? fmaxf(v0, tile[tx][ls + 1]) : v0;
            float p4 = p2;
            if (rem >= 2) p4 = fmaxf(p4, tile[tx][ls + 2]);
            if (rem >= 3) p4 = fmaxf(p4, tile[tx][ls + 3]);

            const size_t o = ((size_t)b * S_ + s) * C_ + (c0 + tx);
            fmT[o] = v0;
            P2[o]  = p2;
            P4[o]  = p4;
        }
    }
}

// ---------------------------------------------------------------------------
// Block-uniform ROI decode (SPATIAL_SCALE == 1.0); matches reference exactly.
// ---------------------------------------------------------------------------
__device__ __forceinline__ void roi_decode(const float* __restrict__ rois, int r,
                                           int& b, int& x0, int& y0,
                                           int& roi_w, int& roi_h)
{
    const float* rp = rois + r * 5;
    b = (int)rp[4];                          // trunc, matches astype(int32)
    // jnp.round == round-half-to-even == rintf
    x0      = (int)rintf(rp[0]);
    y0      = (int)rintf(rp[1]);
    int x1  = (int)rintf(rp[2]);
    int y1  = (int)rintf(rp[3]);
    x0 = min(max(x0, 0), W_ - 1);
    x1 = min(max(x1, 0), W_ - 1);
    y0 = min(max(y0, 0), H_ - 1);
    y1 = min(max(y1, 0), H_ - 1);
    x1 = max(x1, x0 + 1);
    y1 = max(y1, y0 + 1);
    roi_w = x1 - x0;                         // >= 1  (bin widths  <= 8)
    roi_h = y1 - y0;                         // >= 1  (bin heights <= 8)
}

// ---------------------------------------------------------------------------
// Per-bin pooling, R10's serial structure (4 waves x 13 bins, whmax template,
// unroll 2), lane = (channel 0..31, anchor half). All ROI-derived scalars are
// readfirstlane'd -> compiler proves uniformity -> bin-edge/address math on
// the SALU pipe, loads in saddr form; VALU does only the fmax tree.
// Span anchors ws / we-sp union EXACTLY to [ws,we) for ww 1..8 (proven
// R7-R16). Rows: min(hs+kh, he-1) in-window clamp (duplicates, max
// unchanged). Cross-half combine via shfl_xor(32).
// ---------------------------------------------------------------------------
template<int WH>
__device__ __forceinline__ void pool_bins_e(
    const float* __restrict__ fmT, const float* __restrict__ P2,
    const float* __restrict__ P4, float* __restrict__ buf,
    int wv, int lane, int imgCE,
    int x0, int y0, int roi_w, int roi_h)
{
    const int c    = lane & 31;
    const int half = lane >> 5;
    const int start = wv * 12 + (wv ? 1 : 0);
    const int qlast = wv * 12 + 12;

    #pragma unroll 2
    for (int k = 0; k < 13; ++k) {
        int q = start + k;
        q = (q > qlast) ? qlast : q;         // own-last-bin repeat (benign)
        const int ph = q / PW_;
        const int pw = q - ph * PW_;
        const int ws = x0 + (pw * roi_w) / PW_;
        const int we = x0 + ((pw + 1) * roi_w + PW_ - 1) / PW_;
        const int hs = y0 + (ph * roi_h) / PH_;
        const int he = y0 + ((ph + 1) * roi_h + PH_ - 1) / PH_;
        const int ww = we - ws;              // 1..8

        const int sp = (ww >= 4) ? 4 : ((ww >= 2) ? 2 : 1);
        const float* tb = (ww >= 4) ? P4 : ((ww >= 2) ? P2 : fmT);
        const int col = (half ? (we - sp) : ws) * C_;   // per-lane anchor

        float va[WH];
        #pragma unroll
        for (int kh = 0; kh < WH; ++kh) {
            int row = hs + kh;
            row = (row > he - 1) ? (he - 1) : row;      // clamp (in-window)
            va[kh] = tb[imgCE + row * (W_ * C_) + col];
        }
        float m = -FLT_MAX;
        #pragma unroll
        for (int kh = 0; kh < WH; ++kh)
            m = fmaxf(m, va[kh]);

        m = fmaxf(m, __shfl_xor(m, 32));     // combine anchor halves
        if (half == 0)
            buf[q * 33 + c] = m;
    }
}

// ---------------------------------------------------------------------------
// Kernel K2: block = (roi, eighth) -> 2400 blocks x 256 thr = 8 blocks/CU
// (32 waves/CU, 2x R10's latency hiding). Output region per block = 6272 B
// = exactly 49 HBM lines, line-exclusive (6272 % 128 == 0, base % 128 == 0).
// ---------------------------------------------------------------------------
__global__ __launch_bounds__(256) void roi_pool_e2(
    const float* __restrict__ fmT,   // [B, S, C]
    const float* __restrict__ P2,    // [B, S, C]
    const float* __restrict__ P4,    // [B, S, C]
    const float* __restrict__ rois,  // [R, 5]
    float* __restrict__ out)         // [R, C, Q]
{
    __shared__ float buf[Q_ * 33];           // 6468 B

    const int bid = blockIdx.x;
    const int e   = bid & 7;                 // channel-eighth
    const int r   = bid >> 3;                // roi

    const int t    = threadIdx.x;
    const int wv   = t >> 6;                 // wave 0..3
    const int lane = t & 63;

    int b, x0, y0, roi_w, roi_h;
    roi_decode(rois, r, b, x0, y0, roi_w, roi_h);

    // Hoist uniform scalars to SGPRs: all downstream edge/address math goes
    // to the scalar pipe (frees the VALU measured at 52% busy in R16).
    b     = __builtin_amdgcn_readfirstlane(b);
    x0    = __builtin_amdgcn_readfirstlane(x0);
    y0    = __builtin_amdgcn_readfirstlane(y0);
    roi_w = __builtin_amdgcn_readfirstlane(roi_w);
    roi_h = __builtin_amdgcn_readfirstlane(roi_h);

    // exact block-uniform max bin height
    int whmax = 1;
    #pragma unroll
    for (int i = 0; i < PH_; ++i) {
        const int hs = (i * roi_h) / PH_;
        const int he = ((i + 1) * roi_h + PH_ - 1) / PH_;
        whmax = max(whmax, he - hs);
    }

    const int imgCE = b * SC_ + e * CE_ + (lane & 31);   // int32-safe

    switch (whmax) {                         // block-uniform dispatch
        case 1: pool_bins_e<1>(fmT, P2, P4, buf, wv, lane, imgCE, x0, y0, roi_w, roi_h); break;
        case 2: pool_bins_e<2>(fmT, P2, P4, buf, wv, lane, imgCE, x0, y0, roi_w, roi_h); break;
        case 3: pool_bins_e<3>(fmT, P2, P4, buf, wv, lane, imgCE, x0, y0, roi_w, roi_h); break;
        case 4: pool_bins_e<4>(fmT, P2, P4, buf, wv, lane, imgCE, x0, y0, roi_w, roi_h); break;
        case 5: pool_bins_e<5>(fmT, P2, P4, buf, wv, lane, imgCE, x0, y0, roi_w, roi_h); break;
        case 6: pool_bins_e<6>(fmT, P2, P4, buf, wv, lane, imgCE, x0, y0, roi_w, roi_h); break;
        case 7: pool_bins_e<7>(fmT, P2, P4, buf, wv, lane, imgCE, x0, y0, roi_w, roi_h); break;
        default: pool_bins_e<8>(fmT, P2, P4, buf, wv, lane, imgCE, x0, y0, roi_w, roi_h); break;
    }
    __syncthreads();

    // block-exclusive coalesced write: out[r, e*32 .. +32, 0..49) = 6272 B
    float* outp = out + ((size_t)r * C_ + e * CE_) * Q_;
    #pragma unroll
    for (int k = 0; k < 7; ++k) {            // ceil(32*49 / 256) = 7
        const int idx = k * 256 + t;
        if (idx < CE_ * Q_) {
            const int cl = idx / Q_;
            const int q  = idx - cl * Q_;
            outp[idx] = buf[q * 33 + cl];
        }
    }
}

// ---------------------------------------------------------------------------
// Fallback (ws too small): round-1 thread-per-output kernel (proven, 42.7 us).
// ---------------------------------------------------------------------------
__global__ __launch_bounds__(256) void roi_pool_naive(
    const float* __restrict__ fm,    // [B, C, H, W]
    const float* __restrict__ rois,
    float* __restrict__ out)
{
    const int total = R_ * C_ * Q_;
    int t = blockIdx.x * blockDim.x + threadIdx.x;
    if (t >= total) return;
    int q   = t % Q_;
    int tmp = t / Q_;
    int pw  = q % PW_;
    int ph  = q / PW_;
    int c   = tmp % C_;
    int r   = tmp / C_;

    int b, x0, y0, roi_w, roi_h;
    roi_decode(rois, r, b, x0, y0, roi_w, roi_h);

    const int ws = x0 + (pw * roi_w) / PW_;
    const int we = x0 + ((pw + 1) * roi_w + PW_ - 1) / PW_;
    const int hs = y0 + (ph * roi_h) / PH_;
    const int he = y0 + ((ph + 1) * roi_h + PH_ - 1) / PH_;

    const float* p = fm + ((size_t)(b * C_ + c)) * S_;
    float m = -FLT_MAX;
    for (int h = hs; h < he; ++h)
        for (int w = ws; w < we; ++w)
            m = fmaxf(m, p[h * W_ + w]);
    out[t] = m;
}

extern "C" void kernel_launch(void* const* d_in, const int* in_sizes, int n_in,
                              void* d_out, int out_size, void* d_ws, size_t ws_size,
                              hipStream_t stream)
{
    const float* fm   = (const float*)d_in[0];  // [4,256,50,50]
    const float* rois = (const float*)d_in[1];  // [300,5]
    float* out        = (float*)d_out;          // [300,256,7,7]

    const size_t NEED = 3 * (size_t)ARRN * sizeof(float);   // 30.72 MB

    if (ws_size >= NEED) {
        float* fmT = (float*)d_ws;
        float* P2  = fmT + ARRN;
        float* P4  = P2 + ARRN;
        {
            dim3 grid(40, C_ / 64, B_);          // 40 s-tiles x 4 c-tiles x 4 batch
            dim3 block(64, 4, 1);
            transpose_tables<<<grid, block, 0, stream>>>(fm, fmT, P2, P4);
        }
        roi_pool_e2<<<NWG_POOL, 256, 0, stream>>>(fmT, P2, P4, rois, out);
    } else {
        const int total = R_ * C_ * Q_;
        roi_pool_naive<<<(total + 255) / 256, 256, 0, stream>>>(fm, rois, out);
    }
}